// Round 10
// baseline (212.764 us; speedup 1.0000x reference)
//
#include <hip/hip_runtime.h>

// ---------------------------------------------------------------------------
// SimpleGCN: 3x GCNConv(128->128) + ReLU, mean-pool over 64 graphs, linear to 2.
// g = (h@W)*dinv on MATRIX CORES (layer1: split-bf16 3-MFMA; layers2/3: bf16 A,
// 2 MFMAs). g,h stored bf16.
// ELL row = 32 dwords (128B) = TWO independent 64B halves, each with its own
// counter (dword 0 / dword 16) + 30 u16 entries -> ell_fill's per-line atomic
// chain halves, and counter+entry share one line. Edge parity picks the half.
// Aggregate: 1 node/wave (round-8 structure), 8-deep gather pipeline.
// ---------------------------------------------------------------------------

#define THREADS 256
#define ELLD 32    // ELL row stride in dwords (128B)
#define HALFW 30   // u16 entries per half

typedef __attribute__((ext_vector_type(8))) short short8;
typedef __attribute__((ext_vector_type(4))) float f32x4;

__device__ inline unsigned short bf16_1(float a) {
    unsigned u = __float_as_uint(a);
    u += 0x7FFF + ((u >> 16) & 1);
    return (unsigned short)(u >> 16);
}
__device__ inline void bf16_split(float f, unsigned short& hi, unsigned short& lo) {
    unsigned u = __float_as_uint(f);
    unsigned r = u + 0x7FFF + ((u >> 16) & 1);
    hi = (unsigned short)(r >> 16);
    float hf = __uint_as_float((unsigned)hi << 16);
    float lf = f - hf;
    unsigned ul = __float_as_uint(lf);
    lo = (unsigned short)((ul + 0x7FFF + ((ul >> 16) & 1)) >> 16);
}
__device__ inline unsigned pack_bf16(float a, float b) {
    unsigned ua = __float_as_uint(a);
    unsigned ub = __float_as_uint(b);
    ua += 0x7FFF + ((ua >> 16) & 1);
    ub += 0x7FFF + ((ub >> 16) & 1);
    return (ua >> 16) | (ub & 0xFFFF0000u);
}

// ---- fused prep: W-frag prep (blocks 0-2), bounds (block 3), ELL zero ------
__global__ __launch_bounds__(THREADS) void prep_k(const float* __restrict__ W1,
                                                  const float* __restrict__ W2,
                                                  const float* __restrict__ W3,
                                                  unsigned* __restrict__ wf,
                                                  const int* __restrict__ batch,
                                                  int* __restrict__ gstart,
                                                  int* __restrict__ ell,
                                                  int n, int gtot) {
    int b = blockIdx.x;
    if (b < 3) {
        const float* W = (b == 0) ? W1 : (b == 1) ? W2 : W3;
        unsigned* o_hi = wf + (size_t)b * 16384;
        unsigned* o_lo = o_hi + 8192;
        for (int o = threadIdx.x; o < 8192; o += THREADS) {
            int d = o & 3, l = (o >> 2) & 63, ts = o >> 8;
            int s = ts & 3, t = ts >> 2;
            int k = s * 32 + ((l >> 4) << 3) + d * 2;
            int nn = t * 16 + (l & 15);
            float v0 = W[k * 128 + nn];
            float v1 = W[(k + 1) * 128 + nn];
            unsigned short h0, l0, h1, l1;
            bf16_split(v0, h0, l0);
            bf16_split(v1, h1, l1);
            o_hi[o] = (unsigned)h0 | ((unsigned)h1 << 16);
            o_lo[o] = (unsigned)l0 | ((unsigned)l1 << 16);
        }
    } else if (b == 3) {
        int t = threadIdx.x;
        if (t <= gtot) {
            int lo = 0, hi = n;
            while (lo < hi) {
                int mid = (lo + hi) >> 1;
                if (batch[mid] < t) lo = mid + 1; else hi = mid;
            }
            gstart[t] = lo;
        }
    } else {
        int i = (b - 4) * THREADS + threadIdx.x;
        if (i < n) {
            ell[(size_t)i * ELLD] = 0;
            ell[(size_t)i * ELLD + 16] = 0;
        }
    }
}

// ---- fused degree-count + ELL fill: edge parity picks the 64B half ---------
__global__ __launch_bounds__(THREADS) void ell_fill_k(const int* __restrict__ src,
                                                      const int* __restrict__ dst,
                                                      int* __restrict__ ell, int e) {
    int i = blockIdx.x * THREADS + threadIdx.x;
    if (i < e) {
        int d = dst[i];
        int* ctr = ell + (size_t)d * ELLD + ((i & 1) << 4);  // dword 0 or 16
        int pos = atomicAdd(ctr, 1);
        if (pos < HALFW) ((unsigned short*)ctr)[2 + pos] = (unsigned short)src[i];
    }
}

// ---- MFMA GEMM: g16[row][c] = bf16((A@W)[row][c] * dinv[row]) --------------
template <bool ABF16>
__global__ __launch_bounds__(THREADS) void mfma_gemm_k(const void* __restrict__ Av,
                                                       const unsigned* __restrict__ wf,
                                                       const int* __restrict__ ell,
                                                       unsigned short* __restrict__ g16u,
                                                       int n) {
    __shared__ unsigned wls[16384];  // 64KB: [0..8191] hi, [8192..16383] lo
    int tid = threadIdx.x;
    int lane = tid & 63;
    int r0 = blockIdx.x * 64 + (tid >> 6) * 16;

    for (int i = tid; i < 4096; i += THREADS)
        ((uint4*)wls)[i] = ((const uint4*)wf)[i];

    f32x4 acc[8];
#pragma unroll
    for (int t = 0; t < 8; ++t) acc[t] = (f32x4){0.f, 0.f, 0.f, 0.f};

    int arow = min(r0 + (lane & 15), n - 1);
    int kcol = (lane >> 4) << 3;  // 0,8,16,24

    short8 ah[4], al[4];
    if (ABF16) {
        const unsigned short* A = (const unsigned short*)Av;
#pragma unroll
        for (int s = 0; s < 4; ++s)
            ah[s] = *(const short8*)&A[(size_t)arow * 128 + kcol + s * 32];
    } else {
        const float* A = (const float*)Av;
        float4 v0[4], v1[4];
#pragma unroll
        for (int s = 0; s < 4; ++s) {
            v0[s] = *(const float4*)&A[(size_t)arow * 128 + kcol + s * 32];
            v1[s] = *(const float4*)&A[(size_t)arow * 128 + kcol + s * 32 + 4];
        }
#pragma unroll
        for (int s = 0; s < 4; ++s) {
            unsigned short h[8], lo[8];
            bf16_split(v0[s].x, h[0], lo[0]); bf16_split(v0[s].y, h[1], lo[1]);
            bf16_split(v0[s].z, h[2], lo[2]); bf16_split(v0[s].w, h[3], lo[3]);
            bf16_split(v1[s].x, h[4], lo[4]); bf16_split(v1[s].y, h[5], lo[5]);
            bf16_split(v1[s].z, h[6], lo[6]); bf16_split(v1[s].w, h[7], lo[7]);
#pragma unroll
            for (int j = 0; j < 8; ++j) { ah[s][j] = (short)h[j]; al[s][j] = (short)lo[j]; }
        }
    }

    __syncthreads();

#pragma unroll
    for (int s = 0; s < 4; ++s) {
#pragma unroll
        for (int t = 0; t < 8; ++t) {
            int base = (t * 4 + s) * 256 + lane * 4;
            short8 bh = *(short8*)&wls[base];
            short8 bl = *(short8*)&wls[8192 + base];
            acc[t] = __builtin_amdgcn_mfma_f32_16x16x32_bf16(ah[s], bh, acc[t], 0, 0, 0);
            if (!ABF16)
                acc[t] = __builtin_amdgcn_mfma_f32_16x16x32_bf16(al[s], bh, acc[t], 0, 0, 0);
            acc[t] = __builtin_amdgcn_mfma_f32_16x16x32_bf16(ah[s], bl, acc[t], 0, 0, 0);
        }
    }

    int rbase = r0 + ((lane >> 4) << 2);
#pragma unroll
    for (int reg = 0; reg < 4; ++reg) {
        int rr = rbase + reg;
        if (rr < n) {
            int cnt = ell[(size_t)rr * ELLD] + ell[(size_t)rr * ELLD + 16];
            float dv = rsqrtf(1.f + (float)cnt);
#pragma unroll
            for (int t = 0; t < 8; ++t)
                g16u[(size_t)rr * 128 + t * 16 + (lane & 15)] = bf16_1(acc[t][reg] * dv);
        }
    }
}

// ---- aggregate: h[i] = bf16(relu(dinv[i]*(g[i] + sum_{src} g[src]) + b)) ---
// 1 node/wave (round-8 structure). One 128B row load -> counters c0,c1 +
// 60 u16 entries in registers; entry j<d0 from half0, else half1. 8-deep
// predicated gather pipeline, fp32 accumulation.
__global__ __launch_bounds__(THREADS) void aggregate_k(const unsigned* __restrict__ g16,
                                                       const unsigned* __restrict__ ell,
                                                       const float* __restrict__ bias,
                                                       unsigned* __restrict__ h16,
                                                       int n) {
    int wave = (blockIdx.x * THREADS + threadIdx.x) >> 6;
    int lane = threadIdx.x & 63;
    if (wave >= n) return;

    unsigned v = ell[(size_t)wave * ELLD + (lane & 31)];
    int c0 = (int)__shfl(v, 0);
    int c1 = (int)__shfl(v, 16);
    int cnt_true = c0 + c1;
    int d0 = min(c0, HALFW);
    int deg = d0 + min(c1, HALFW);
    int degm1 = max(deg - 1, 0);

    unsigned us = g16[(size_t)wave * 64 + lane];
    float ax0 = __uint_as_float(us << 16);
    float ay0 = __uint_as_float(us & 0xFFFF0000u);
    float ax1 = 0.f, ay1 = 0.f, ax2 = 0.f, ay2 = 0.f, ax3 = 0.f, ay3 = 0.f;
    float ax4 = 0.f, ay4 = 0.f, ax5 = 0.f, ay5 = 0.f, ax6 = 0.f, ay6 = 0.f;
    float ax7 = 0.f, ay7 = 0.f;

    for (int k = 0; k < deg; k += 8) {
        int s[8];
        float m[8];
#pragma unroll
        for (int j = 0; j < 8; ++j) {
            int jj = min(k + j, degm1);
            int in0 = jj < d0;
            int rel = in0 ? jj : jj - d0;
            int lsrc = (in0 ? 1 : 17) + (rel >> 1);
            unsigned dw = __shfl(v, lsrc);
            s[j] = (int)((dw >> ((rel & 1) * 16)) & 0xFFFFu);
            m[j] = (k + j < deg) ? 1.f : 0.f;
        }
        unsigned u0 = g16[(size_t)s[0] * 64 + lane];
        unsigned u1 = g16[(size_t)s[1] * 64 + lane];
        unsigned u2 = g16[(size_t)s[2] * 64 + lane];
        unsigned u3 = g16[(size_t)s[3] * 64 + lane];
        unsigned u4 = g16[(size_t)s[4] * 64 + lane];
        unsigned u5 = g16[(size_t)s[5] * 64 + lane];
        unsigned u6 = g16[(size_t)s[6] * 64 + lane];
        unsigned u7 = g16[(size_t)s[7] * 64 + lane];
        ax0 = fmaf(m[0], __uint_as_float(u0 << 16), ax0);
        ay0 = fmaf(m[0], __uint_as_float(u0 & 0xFFFF0000u), ay0);
        ax1 = fmaf(m[1], __uint_as_float(u1 << 16), ax1);
        ay1 = fmaf(m[1], __uint_as_float(u1 & 0xFFFF0000u), ay1);
        ax2 = fmaf(m[2], __uint_as_float(u2 << 16), ax2);
        ay2 = fmaf(m[2], __uint_as_float(u2 & 0xFFFF0000u), ay2);
        ax3 = fmaf(m[3], __uint_as_float(u3 << 16), ax3);
        ay3 = fmaf(m[3], __uint_as_float(u3 & 0xFFFF0000u), ay3);
        ax4 = fmaf(m[4], __uint_as_float(u4 << 16), ax4);
        ay4 = fmaf(m[4], __uint_as_float(u4 & 0xFFFF0000u), ay4);
        ax5 = fmaf(m[5], __uint_as_float(u5 << 16), ax5);
        ay5 = fmaf(m[5], __uint_as_float(u5 & 0xFFFF0000u), ay5);
        ax6 = fmaf(m[6], __uint_as_float(u6 << 16), ax6);
        ay6 = fmaf(m[6], __uint_as_float(u6 & 0xFFFF0000u), ay6);
        ax7 = fmaf(m[7], __uint_as_float(u7 << 16), ax7);
        ay7 = fmaf(m[7], __uint_as_float(u7 & 0xFFFF0000u), ay7);
    }
    ax0 += (ax1 + ax2) + (ax3 + ax4) + (ax5 + ax6) + ax7;
    ay0 += (ay1 + ay2) + (ay3 + ay4) + (ay5 + ay6) + ay7;

    float d = rsqrtf(1.f + (float)cnt_true);
    float2 bb = ((const float2*)bias)[lane];
    float ox = fmaxf(fmaf(d, ax0, bb.x), 0.f);
    float oy = fmaxf(fmaf(d, ay0, bb.y), 0.f);
    h16[(size_t)wave * 64 + lane] = pack_bf16(ox, oy);
}

// ---- pooling: per (graph, slice) partial sums over bf16 h ------------------
#define PSLICES 8
__global__ __launch_bounds__(THREADS) void pool_k(const unsigned* __restrict__ h16,
                                                  const int* __restrict__ gstart,
                                                  float* __restrict__ partial) {
    int gph = blockIdx.x, s = blockIdx.y;
    int start = gstart[gph], end = gstart[gph + 1];
    int len = end - start;
    int chunk = (len + PSLICES - 1) / PSLICES;
    int rs = start + s * chunk;
    int re = min(rs + chunk, end);
    int c = threadIdx.x & 63, half = threadIdx.x >> 6;
    float sx = 0.f, sy = 0.f;
    for (int r = rs + half; r < re; r += 4) {
        unsigned u = h16[(size_t)r * 64 + c];
        sx += __uint_as_float(u << 16);
        sy += __uint_as_float(u & 0xFFFF0000u);
    }
    __shared__ float shx[4][64], shy[4][64];
    shx[half][c] = sx;
    shy[half][c] = sy;
    __syncthreads();
    if (half == 0) {
        sx = shx[0][c] + shx[1][c] + shx[2][c] + shx[3][c];
        sy = shy[0][c] + shy[1][c] + shy[2][c] + shy[3][c];
        partial[(gph * PSLICES + s) * 128 + c * 2] = sx;
        partial[(gph * PSLICES + s) * 128 + c * 2 + 1] = sy;
    }
}

// ---- final: out[g][j] = dot(mean_h[g], Wl[:,j]) + bl[j] --------------------
__global__ __launch_bounds__(128) void final_k(const float* __restrict__ partial,
                                               const int* __restrict__ gstart,
                                               const float* __restrict__ Wl,
                                               const float* __restrict__ bl,
                                               float* __restrict__ out, int gtot) {
    int t = threadIdx.x;
    int gph = t >> 1, j = t & 1;
    if (gph >= gtot) return;
    float cnt = fmaxf((float)(gstart[gph + 1] - gstart[gph]), 1.f);
    float sacc = 0.f;
    for (int k = 0; k < 128; ++k) {
        float v = 0.f;
#pragma unroll
        for (int sb = 0; sb < PSLICES; ++sb)
            v += partial[(gph * PSLICES + sb) * 128 + k];
        sacc = fmaf(v, Wl[k * 2 + j], sacc);
    }
    out[gph * 2 + j] = sacc / cnt + bl[j];
}

// ---------------------------------------------------------------------------
extern "C" void kernel_launch(void* const* d_in, const int* in_sizes, int n_in,
                              void* d_out, int out_size, void* d_ws, size_t ws_size,
                              hipStream_t stream) {
    const float* x  = (const float*)d_in[0];
    const int* ei   = (const int*)d_in[1];
    const int* batch= (const int*)d_in[2];
    const float* W1 = (const float*)d_in[3];
    const float* b1 = (const float*)d_in[4];
    const float* W2 = (const float*)d_in[5];
    const float* b2 = (const float*)d_in[6];
    const float* W3 = (const float*)d_in[7];
    const float* b3 = (const float*)d_in[8];
    const float* Wl = (const float*)d_in[9];
    const float* bl = (const float*)d_in[10];
    float* out = (float*)d_out;

    const int N = in_sizes[0] / 128;
    const int E = in_sizes[1] / 2;
    const int G = out_size / 2;
    const int* src = ei;
    const int* dst = ei + E;

    char* ws = (char*)d_ws;
    size_t off = 0;
    auto alloc = [&](size_t bytes) -> void* {
        void* p = ws + off;
        off = (off + bytes + 255) & ~(size_t)255;
        return p;
    };
    unsigned* g16  = (unsigned*)alloc((size_t)N * 64 * 4);    // bf16 [N][128]
    unsigned* h16  = (unsigned*)alloc((size_t)N * 64 * 4);    // bf16 [N][128]
    int* ell       = (int*)alloc((size_t)N * ELLD * 4);       // 2x[ctr|30 u16] per row
    unsigned* wf   = (unsigned*)alloc((size_t)3 * 16384 * 4); // frag-ordered W hi/lo
    float* partial = (float*)alloc((size_t)G * PSLICES * 128 * 4);
    int* gstart    = (int*)alloc((size_t)(G + 1) * 4);
    (void)ws_size;

    int gridE = (E + THREADS - 1) / THREADS;
    int gridN = (N + THREADS - 1) / THREADS;

    prep_k<<<4 + gridN, THREADS, 0, stream>>>(W1, W2, W3, wf, batch, gstart, ell, N, G);
    ell_fill_k<<<gridE, THREADS, 0, stream>>>(src, dst, ell, E);

    int gemmGrid = (N + 63) / 64;
    int aggGrid = (N + 3) / 4;  // 4 waves/block, 1 node/wave
    unsigned short* g16u = (unsigned short*)g16;

    // layer 1 (A = x, fp32)
    mfma_gemm_k<false><<<gemmGrid, THREADS, 0, stream>>>(x, wf, ell, g16u, N);
    aggregate_k<<<aggGrid, THREADS, 0, stream>>>(g16, (const unsigned*)ell, b1, h16, N);
    // layer 2 (A = h16, bf16)
    mfma_gemm_k<true><<<gemmGrid, THREADS, 0, stream>>>(h16, wf + 16384, ell, g16u, N);
    aggregate_k<<<aggGrid, THREADS, 0, stream>>>(g16, (const unsigned*)ell, b2, h16, N);
    // layer 3
    mfma_gemm_k<true><<<gemmGrid, THREADS, 0, stream>>>(h16, wf + 32768, ell, g16u, N);
    aggregate_k<<<aggGrid, THREADS, 0, stream>>>(g16, (const unsigned*)ell, b3, h16, N);

    // pooling + head
    dim3 poolGrid(G, PSLICES);
    pool_k<<<poolGrid, THREADS, 0, stream>>>(h16, gstart, partial);
    final_k<<<1, 128, 0, stream>>>(partial, gstart, Wl, bl, out, G);
}

// Round 11
// 181.983 us; speedup vs baseline: 1.1691x; 1.1691x over previous
//
#include <hip/hip_runtime.h>

// ---------------------------------------------------------------------------
// SimpleGCN: 3x GCNConv(128->128) + ReLU, mean-pool over 64 graphs, linear to 2.
// Round-8 structure (known-good) + g stored as FP8 E4M3 (HW cvt, 128B rows):
// aggregate is fabric-byte-bound, fp8 halves gather bytes. h stays bf16
// (GEMM A-fragments + error budget). fp32 accumulation everywhere.
// ELL rows of 64 ints: [0]=counter, [1..48]=src ids (round-8 layout).
// ---------------------------------------------------------------------------

#define THREADS 256
#define ELLW 48
#define ELLS 64   // ELL row stride in ints (256B)

typedef __attribute__((ext_vector_type(8))) short short8;
typedef __attribute__((ext_vector_type(4))) float f32x4;
typedef __attribute__((ext_vector_type(2))) float floatx2;

__device__ inline void bf16_split(float f, unsigned short& hi, unsigned short& lo) {
    unsigned u = __float_as_uint(f);
    unsigned r = u + 0x7FFF + ((u >> 16) & 1);
    hi = (unsigned short)(r >> 16);
    float hf = __uint_as_float((unsigned)hi << 16);
    float lf = f - hf;
    unsigned ul = __float_as_uint(lf);
    lo = (unsigned short)((ul + 0x7FFF + ((ul >> 16) & 1)) >> 16);
}
__device__ inline unsigned pack_bf16(float a, float b) {
    unsigned ua = __float_as_uint(a);
    unsigned ub = __float_as_uint(b);
    ua += 0x7FFF + ((ua >> 16) & 1);
    ub += 0x7FFF + ((ub >> 16) & 1);
    return (ua >> 16) | (ub & 0xFFFF0000u);
}
// 2x fp8 e4m3 -> 2x f32 (hardware convert, denormal-correct)
__device__ inline floatx2 fp8x2_to_f32(unsigned short u) {
    return __builtin_amdgcn_cvt_pk_f32_fp8((int)(unsigned)u, false);
}
// f32 -> fp8 e4m3 byte (hardware convert)
__device__ inline unsigned char f32_to_fp8(float v) {
    int pk = __builtin_amdgcn_cvt_pk_fp8_f32(v, v, 0, false);
    return (unsigned char)(pk & 0xFF);
}

// ---- fused prep: W-frag prep (blocks 0-2), bounds (block 3), ELL zero ------
__global__ __launch_bounds__(THREADS) void prep_k(const float* __restrict__ W1,
                                                  const float* __restrict__ W2,
                                                  const float* __restrict__ W3,
                                                  unsigned* __restrict__ wf,
                                                  const int* __restrict__ batch,
                                                  int* __restrict__ gstart,
                                                  int* __restrict__ ell,
                                                  int n, int gtot) {
    int b = blockIdx.x;
    if (b < 3) {
        const float* W = (b == 0) ? W1 : (b == 1) ? W2 : W3;
        unsigned* o_hi = wf + (size_t)b * 16384;
        unsigned* o_lo = o_hi + 8192;
        for (int o = threadIdx.x; o < 8192; o += THREADS) {
            int d = o & 3, l = (o >> 2) & 63, ts = o >> 8;
            int s = ts & 3, t = ts >> 2;
            int k = s * 32 + ((l >> 4) << 3) + d * 2;
            int nn = t * 16 + (l & 15);
            float v0 = W[k * 128 + nn];
            float v1 = W[(k + 1) * 128 + nn];
            unsigned short h0, l0, h1, l1;
            bf16_split(v0, h0, l0);
            bf16_split(v1, h1, l1);
            o_hi[o] = (unsigned)h0 | ((unsigned)h1 << 16);
            o_lo[o] = (unsigned)l0 | ((unsigned)l1 << 16);
        }
    } else if (b == 3) {
        int t = threadIdx.x;
        if (t <= gtot) {
            int lo = 0, hi = n;
            while (lo < hi) {
                int mid = (lo + hi) >> 1;
                if (batch[mid] < t) lo = mid + 1; else hi = mid;
            }
            gstart[t] = lo;
        }
    } else {
        int i = (b - 4) * THREADS + threadIdx.x;
        if (i < n) ell[(size_t)i * ELLS] = 0;
    }
}

// ---- fused degree-count + ELL fill (counter embedded in row) ---------------
__global__ __launch_bounds__(THREADS) void ell_fill_k(const int* __restrict__ src,
                                                      const int* __restrict__ dst,
                                                      int* __restrict__ ell, int e) {
    int i = blockIdx.x * THREADS + threadIdx.x;
    if (i < e) {
        int d = dst[i];
        int* row = ell + (size_t)d * ELLS;
        int pos = atomicAdd(row, 1);
        if (pos < ELLW) row[1 + pos] = src[i];
    }
}

// ---- MFMA GEMM: g8[row][c] = fp8((A@W)[row][c] * dinv[row]) ----------------
// ABF16=false: A fp32 (layer 1), split hi/lo, 3 MFMAs/step.
// ABF16=true:  A bf16 (h), 2 MFMAs/step.
template <bool ABF16>
__global__ __launch_bounds__(THREADS) void mfma_gemm_k(const void* __restrict__ Av,
                                                       const unsigned* __restrict__ wf,
                                                       const int* __restrict__ ell,
                                                       unsigned char* __restrict__ g8,
                                                       int n) {
    __shared__ unsigned wls[16384];  // 64KB: [0..8191] hi, [8192..16383] lo
    int tid = threadIdx.x;
    int lane = tid & 63;
    int r0 = blockIdx.x * 64 + (tid >> 6) * 16;

    for (int i = tid; i < 4096; i += THREADS)
        ((uint4*)wls)[i] = ((const uint4*)wf)[i];

    f32x4 acc[8];
#pragma unroll
    for (int t = 0; t < 8; ++t) acc[t] = (f32x4){0.f, 0.f, 0.f, 0.f};

    int arow = min(r0 + (lane & 15), n - 1);
    int kcol = (lane >> 4) << 3;  // 0,8,16,24

    short8 ah[4], al[4];
    if (ABF16) {
        const unsigned short* A = (const unsigned short*)Av;
#pragma unroll
        for (int s = 0; s < 4; ++s)
            ah[s] = *(const short8*)&A[(size_t)arow * 128 + kcol + s * 32];
    } else {
        const float* A = (const float*)Av;
        float4 v0[4], v1[4];
#pragma unroll
        for (int s = 0; s < 4; ++s) {
            v0[s] = *(const float4*)&A[(size_t)arow * 128 + kcol + s * 32];
            v1[s] = *(const float4*)&A[(size_t)arow * 128 + kcol + s * 32 + 4];
        }
#pragma unroll
        for (int s = 0; s < 4; ++s) {
            unsigned short h[8], lo[8];
            bf16_split(v0[s].x, h[0], lo[0]); bf16_split(v0[s].y, h[1], lo[1]);
            bf16_split(v0[s].z, h[2], lo[2]); bf16_split(v0[s].w, h[3], lo[3]);
            bf16_split(v1[s].x, h[4], lo[4]); bf16_split(v1[s].y, h[5], lo[5]);
            bf16_split(v1[s].z, h[6], lo[6]); bf16_split(v1[s].w, h[7], lo[7]);
#pragma unroll
            for (int j = 0; j < 8; ++j) { ah[s][j] = (short)h[j]; al[s][j] = (short)lo[j]; }
        }
    }

    __syncthreads();

#pragma unroll
    for (int s = 0; s < 4; ++s) {
#pragma unroll
        for (int t = 0; t < 8; ++t) {
            int base = (t * 4 + s) * 256 + lane * 4;
            short8 bh = *(short8*)&wls[base];
            short8 bl = *(short8*)&wls[8192 + base];
            acc[t] = __builtin_amdgcn_mfma_f32_16x16x32_bf16(ah[s], bh, acc[t], 0, 0, 0);
            if (!ABF16)
                acc[t] = __builtin_amdgcn_mfma_f32_16x16x32_bf16(al[s], bh, acc[t], 0, 0, 0);
            acc[t] = __builtin_amdgcn_mfma_f32_16x16x32_bf16(ah[s], bl, acc[t], 0, 0, 0);
        }
    }

    // epilogue: D[row=(l>>4)*4+reg][col=t*16+(l&15)], dinv from ELL counter
    int rbase = r0 + ((lane >> 4) << 2);
#pragma unroll
    for (int reg = 0; reg < 4; ++reg) {
        int rr = rbase + reg;
        if (rr < n) {
            float dv = rsqrtf(1.f + (float)ell[(size_t)rr * ELLS]);
#pragma unroll
            for (int t = 0; t < 8; ++t)
                g8[(size_t)rr * 128 + t * 16 + (lane & 15)] = f32_to_fp8(acc[t][reg] * dv);
        }
    }
}

// ---- aggregate: h[i] = bf16(relu(dinv[i]*(g[i] + sum_{src} g[src]) + b)) ---
// Round-8 structure: 1 node/wave, indices in registers via one 256B ELL-row
// load + __shfl, 8-deep predicated gather pipeline. g rows are 128B fp8;
// lane loads ushort (2 fp8 = its 2 channels), HW cvt to f32, fp32 accum.
__global__ __launch_bounds__(THREADS) void aggregate_k(const unsigned short* __restrict__ g8u,
                                                       const int* __restrict__ ell,
                                                       const float* __restrict__ bias,
                                                       unsigned* __restrict__ h16,
                                                       int n) {
    int wave = (blockIdx.x * THREADS + threadIdx.x) >> 6;
    int lane = threadIdx.x & 63;
    if (wave >= n) return;

    int v = ell[(size_t)wave * ELLS + lane];  // lane 0: count, lane k: src[k-1]
    int cnt_true = __shfl(v, 0);
    int deg = min(cnt_true, ELLW);

    floatx2 fs = fp8x2_to_f32(g8u[(size_t)wave * 64 + lane]);  // self-loop
    float ax0 = fs.x, ay0 = fs.y;
    float ax1 = 0.f, ay1 = 0.f, ax2 = 0.f, ay2 = 0.f, ax3 = 0.f, ay3 = 0.f;
    float ax4 = 0.f, ay4 = 0.f, ax5 = 0.f, ay5 = 0.f, ax6 = 0.f, ay6 = 0.f;
    float ax7 = 0.f, ay7 = 0.f;

    for (int k = 0; k < deg; k += 8) {
        int s0 = __shfl(v, k + 1);
        int s1 = __shfl(v, min(k + 2, deg));
        int s2 = __shfl(v, min(k + 3, deg));
        int s3 = __shfl(v, min(k + 4, deg));
        int s4 = __shfl(v, min(k + 5, deg));
        int s5 = __shfl(v, min(k + 6, deg));
        int s6 = __shfl(v, min(k + 7, deg));
        int s7 = __shfl(v, min(k + 8, deg));
        float m1 = (k + 1 < deg) ? 1.f : 0.f;
        float m2 = (k + 2 < deg) ? 1.f : 0.f;
        float m3 = (k + 3 < deg) ? 1.f : 0.f;
        float m4 = (k + 4 < deg) ? 1.f : 0.f;
        float m5 = (k + 5 < deg) ? 1.f : 0.f;
        float m6 = (k + 6 < deg) ? 1.f : 0.f;
        float m7 = (k + 7 < deg) ? 1.f : 0.f;
        unsigned short q0 = g8u[(size_t)s0 * 64 + lane];
        unsigned short q1 = g8u[(size_t)s1 * 64 + lane];
        unsigned short q2 = g8u[(size_t)s2 * 64 + lane];
        unsigned short q3 = g8u[(size_t)s3 * 64 + lane];
        unsigned short q4 = g8u[(size_t)s4 * 64 + lane];
        unsigned short q5 = g8u[(size_t)s5 * 64 + lane];
        unsigned short q6 = g8u[(size_t)s6 * 64 + lane];
        unsigned short q7 = g8u[(size_t)s7 * 64 + lane];
        floatx2 f0 = fp8x2_to_f32(q0);
        floatx2 f1 = fp8x2_to_f32(q1);
        floatx2 f2 = fp8x2_to_f32(q2);
        floatx2 f3 = fp8x2_to_f32(q3);
        floatx2 f4 = fp8x2_to_f32(q4);
        floatx2 f5 = fp8x2_to_f32(q5);
        floatx2 f6 = fp8x2_to_f32(q6);
        floatx2 f7 = fp8x2_to_f32(q7);
        ax0 += f0.x;                ay0 += f0.y;
        ax1 = fmaf(m1, f1.x, ax1);  ay1 = fmaf(m1, f1.y, ay1);
        ax2 = fmaf(m2, f2.x, ax2);  ay2 = fmaf(m2, f2.y, ay2);
        ax3 = fmaf(m3, f3.x, ax3);  ay3 = fmaf(m3, f3.y, ay3);
        ax4 = fmaf(m4, f4.x, ax4);  ay4 = fmaf(m4, f4.y, ay4);
        ax5 = fmaf(m5, f5.x, ax5);  ay5 = fmaf(m5, f5.y, ay5);
        ax6 = fmaf(m6, f6.x, ax6);  ay6 = fmaf(m6, f6.y, ay6);
        ax7 = fmaf(m7, f7.x, ax7);  ay7 = fmaf(m7, f7.y, ay7);
    }
    ax0 += (ax1 + ax2) + (ax3 + ax4) + (ax5 + ax6) + ax7;
    ay0 += (ay1 + ay2) + (ay3 + ay4) + (ay5 + ay6) + ay7;

    float d = rsqrtf(1.f + (float)cnt_true);
    float2 bb = ((const float2*)bias)[lane];
    float ox = fmaxf(fmaf(d, ax0, bb.x), 0.f);
    float oy = fmaxf(fmaf(d, ay0, bb.y), 0.f);
    h16[(size_t)wave * 64 + lane] = pack_bf16(ox, oy);
}

// ---- pooling: per (graph, slice) partial sums over bf16 h ------------------
#define PSLICES 8
__global__ __launch_bounds__(THREADS) void pool_k(const unsigned* __restrict__ h16,
                                                  const int* __restrict__ gstart,
                                                  float* __restrict__ partial) {
    int gph = blockIdx.x, s = blockIdx.y;
    int start = gstart[gph], end = gstart[gph + 1];
    int len = end - start;
    int chunk = (len + PSLICES - 1) / PSLICES;
    int rs = start + s * chunk;
    int re = min(rs + chunk, end);
    int c = threadIdx.x & 63, half = threadIdx.x >> 6;
    float sx = 0.f, sy = 0.f;
    for (int r = rs + half; r < re; r += 4) {
        unsigned u = h16[(size_t)r * 64 + c];
        sx += __uint_as_float(u << 16);
        sy += __uint_as_float(u & 0xFFFF0000u);
    }
    __shared__ float shx[4][64], shy[4][64];
    shx[half][c] = sx;
    shy[half][c] = sy;
    __syncthreads();
    if (half == 0) {
        sx = shx[0][c] + shx[1][c] + shx[2][c] + shx[3][c];
        sy = shy[0][c] + shy[1][c] + shy[2][c] + shy[3][c];
        partial[(gph * PSLICES + s) * 128 + c * 2] = sx;
        partial[(gph * PSLICES + s) * 128 + c * 2 + 1] = sy;
    }
}

// ---- final: out[g][j] = dot(mean_h[g], Wl[:,j]) + bl[j] --------------------
__global__ __launch_bounds__(128) void final_k(const float* __restrict__ partial,
                                               const int* __restrict__ gstart,
                                               const float* __restrict__ Wl,
                                               const float* __restrict__ bl,
                                               float* __restrict__ out, int gtot) {
    int t = threadIdx.x;
    int gph = t >> 1, j = t & 1;
    if (gph >= gtot) return;
    float cnt = fmaxf((float)(gstart[gph + 1] - gstart[gph]), 1.f);
    float sacc = 0.f;
    for (int k = 0; k < 128; ++k) {
        float v = 0.f;
#pragma unroll
        for (int sb = 0; sb < PSLICES; ++sb)
            v += partial[(gph * PSLICES + sb) * 128 + k];
        sacc = fmaf(v, Wl[k * 2 + j], sacc);
    }
    out[gph * 2 + j] = sacc / cnt + bl[j];
}

// ---------------------------------------------------------------------------
extern "C" void kernel_launch(void* const* d_in, const int* in_sizes, int n_in,
                              void* d_out, int out_size, void* d_ws, size_t ws_size,
                              hipStream_t stream) {
    const float* x  = (const float*)d_in[0];
    const int* ei   = (const int*)d_in[1];
    const int* batch= (const int*)d_in[2];
    const float* W1 = (const float*)d_in[3];
    const float* b1 = (const float*)d_in[4];
    const float* W2 = (const float*)d_in[5];
    const float* b2 = (const float*)d_in[6];
    const float* W3 = (const float*)d_in[7];
    const float* b3 = (const float*)d_in[8];
    const float* Wl = (const float*)d_in[9];
    const float* bl = (const float*)d_in[10];
    float* out = (float*)d_out;

    const int N = in_sizes[0] / 128;
    const int E = in_sizes[1] / 2;
    const int G = out_size / 2;
    const int* src = ei;
    const int* dst = ei + E;

    char* ws = (char*)d_ws;
    size_t off = 0;
    auto alloc = [&](size_t bytes) -> void* {
        void* p = ws + off;
        off = (off + bytes + 255) & ~(size_t)255;
        return p;
    };
    unsigned char* g8 = (unsigned char*)alloc((size_t)N * 128); // fp8 [N][128]
    unsigned* h16  = (unsigned*)alloc((size_t)N * 64 * 4);      // bf16 [N][128]
    int* ell       = (int*)alloc((size_t)N * ELLS * 4);         // [cnt|48 srcs|pad]
    unsigned* wf   = (unsigned*)alloc((size_t)3 * 16384 * 4);   // frag-ordered W hi/lo
    float* partial = (float*)alloc((size_t)G * PSLICES * 128 * 4);
    int* gstart    = (int*)alloc((size_t)(G + 1) * 4);
    (void)ws_size;

    int gridE = (E + THREADS - 1) / THREADS;
    int gridN = (N + THREADS - 1) / THREADS;

    prep_k<<<4 + gridN, THREADS, 0, stream>>>(W1, W2, W3, wf, batch, gstart, ell, N, G);
    ell_fill_k<<<gridE, THREADS, 0, stream>>>(src, dst, ell, E);

    int gemmGrid = (N + 63) / 64;
    int aggGrid = (N + 3) / 4;  // 4 waves/block, 1 node/wave
    const unsigned short* g8u = (const unsigned short*)g8;

    // layer 1 (A = x, fp32)
    mfma_gemm_k<false><<<gemmGrid, THREADS, 0, stream>>>(x, wf, ell, g8, N);
    aggregate_k<<<aggGrid, THREADS, 0, stream>>>(g8u, ell, b1, h16, N);
    // layer 2 (A = h16, bf16)
    mfma_gemm_k<true><<<gemmGrid, THREADS, 0, stream>>>(h16, wf + 16384, ell, g8, N);
    aggregate_k<<<aggGrid, THREADS, 0, stream>>>(g8u, ell, b2, h16, N);
    // layer 3
    mfma_gemm_k<true><<<gemmGrid, THREADS, 0, stream>>>(h16, wf + 32768, ell, g8, N);
    aggregate_k<<<aggGrid, THREADS, 0, stream>>>(g8u, ell, b3, h16, N);

    // pooling + head
    dim3 poolGrid(G, PSLICES);
    pool_k<<<poolGrid, THREADS, 0, stream>>>(h16, gstart, partial);
    final_k<<<1, 128, 0, stream>>>(partial, gstart, Wl, bl, out, G);
}